// Round 10
// baseline (328.535 us; speedup 1.0000x reference)
//
#include <hip/hip_runtime.h>
#include <hip/hip_bf16.h>

#define B 2
#define C 64
#define N 4096          // 16*16*16
#define EPS 1e-5f
#define KSEG 16
// 0.125 * log2(e): fold softmax scale AND exp->exp2 conversion into q
#define QSCALE_LOG2E 0.18033688f

using short8 = __attribute__((ext_vector_type(8))) short;
using f32x16 = __attribute__((ext_vector_type(16))) float;

__device__ inline short f2bf(float f) {
  __hip_bfloat16 h = __float2bfloat16(f);
  union { __hip_bfloat16 h; short s; } u; u.h = h; return u.s;
}
__device__ inline float bf2f(short s) {
  union { unsigned u; float f; } u;
  u.u = ((unsigned)(unsigned short)s) << 16;
  return u.f;
}
__device__ inline int packbf(float a, float b) {
  return (int)((unsigned short)f2bf(a) | ((unsigned)(unsigned short)f2bf(b) << 16));
}

// softmax (exp2 domain, no max) + pack P into two PV B-fragments (R4 verbatim)
__device__ inline void softpack(f32x16& s, int hi, float& lsum,
                                short8& p0, short8& p1) {
  float ps = 0.f;
#pragma unroll
  for (int i = 0; i < 16; ++i) { s[i] = exp2f(s[i]); ps += s[i]; }
  lsum += ps;   // cross-pair shfl deferred to epilogue (linear)
  union U { int i[4]; short8 v; } f0, f1;
  {
    int x0 = packbf(s[0], s[1]), z0 = packbf(s[2], s[3]);
    int y0 = packbf(s[4], s[5]), w0 = packbf(s[6], s[7]);
    int xs = __shfl_xor(x0, 32), zs = __shfl_xor(z0, 32);
    int ys = __shfl_xor(y0, 32), ws2 = __shfl_xor(w0, 32);
    f0.i[0] = hi ? ys : x0; f0.i[1] = hi ? ws2 : z0;
    f0.i[2] = hi ? y0 : xs; f0.i[3] = hi ? w0 : zs;
  }
  {
    int x0 = packbf(s[8], s[9]), z0 = packbf(s[10], s[11]);
    int y0 = packbf(s[12], s[13]), w0 = packbf(s[14], s[15]);
    int xs = __shfl_xor(x0, 32), zs = __shfl_xor(z0, 32);
    int ys = __shfl_xor(y0, 32), ws2 = __shfl_xor(w0, 32);
    f1.i[0] = hi ? ys : x0; f1.i[1] = hi ? ws2 : z0;
    f1.i[2] = hi ? y0 : xs; f1.i[3] = hi ? w0 : zs;
  }
  p0 = f0.v; p1 = f1.v;
}

// ---------------- GroupNorm partial sums (R4 verbatim) ----------------
__global__ __launch_bounds__(256) void gn_part_kernel(
    const float* __restrict__ x, float2* __restrict__ part) {
  int blk = blockIdx.x;
  int bg = blk >> 4, sl = blk & 15;
  const float4* xv = (const float4*)(x + (size_t)bg * 4 * N) + sl * 256;
  int tid = threadIdx.x;
  float4 v = xv[tid];
  float s = v.x + v.y + v.z + v.w;
  float s2 = v.x * v.x + v.y * v.y + v.z * v.z + v.w * v.w;
  __shared__ float ss[256], ss2[256];
  ss[tid] = s; ss2[tid] = s2;
  __syncthreads();
  for (int st = 128; st > 0; st >>= 1) {
    if (tid < st) { ss[tid] += ss[tid + st]; ss2[tid] += ss2[tid + st]; }
    __syncthreads();
  }
  if (tid == 0) part[blk] = make_float2(ss[0], ss2[0]);
}

// ------------- fused gn-finalize + norm + q/k/v conv (R6-proven fold) -------
__global__ __launch_bounds__(256) void qkvf_kernel(
    const float* __restrict__ x, const float2* __restrict__ part,
    const float* __restrict__ gw, const float* __restrict__ gb,
    const float* __restrict__ qw, const float* __restrict__ qb,
    const float* __restrict__ kw, const float* __restrict__ kb,
    const float* __restrict__ vw, const float* __restrict__ vb,
    short* __restrict__ q_t, short* __restrict__ k_t, short* __restrict__ v_b) {
  int o0 = blockIdx.y * 8, b = blockIdx.z;
  int tid = threadIdx.x;
  __shared__ float asl[C], bsl[C];
  if (tid < C) {
    int c = tid, g = c >> 2;
    int bg = b * 16 + g;
    float s = 0.f, s2 = 0.f;
#pragma unroll
    for (int sl = 0; sl < 16; ++sl) {
      float2 p = part[bg * 16 + sl];
      s += p.x; s2 += p.y;
    }
    float mean = s * (1.f / 16384.f);
    float var = s2 * (1.f / 16384.f) - mean * mean;
    float inv = rsqrtf(var + EPS);
    float a = inv * gw[c];
    asl[c] = a;
    bsl[c] = gb[c] - mean * a;
  }
  __syncthreads();
  int pos = blockIdx.x * 256 + tid;
  const float* xp = x + (size_t)b * C * N + pos;
  float sq[8], sk[8], sv[8];
#pragma unroll
  for (int j = 0; j < 8; ++j) { sq[j] = 0.f; sk[j] = 0.f; sv[j] = 0.f; }
#pragma unroll
  for (int c = 0; c < C; ++c) {
    float hv = fmaf(xp[(size_t)c * N], asl[c], bsl[c]);
#pragma unroll
    for (int j = 0; j < 8; ++j) {
      sq[j] = fmaf(qw[(o0 + j) * C + c], hv, sq[j]);
      sk[j] = fmaf(kw[(o0 + j) * C + c], hv, sk[j]);
      sv[j] = fmaf(vw[(o0 + j) * C + c], hv, sv[j]);
    }
  }
  size_t ti = ((size_t)b * N + pos) * C;
  short8 qv, kv;
#pragma unroll
  for (int j = 0; j < 8; ++j) {
    qv[j] = f2bf((sq[j] + qb[o0 + j]) * QSCALE_LOG2E);
    kv[j] = f2bf(sk[j] + kb[o0 + j]);
  }
  *(short8*)&q_t[ti + o0] = qv;
  *(short8*)&k_t[ti + o0] = kv;
#pragma unroll
  for (int j = 0; j < 8; ++j)
    v_b[((size_t)b * C + o0 + j) * N + pos] = f2bf(sv[j] + vb[o0 + j]);
}

// ---------------- MFMA flash attention (R4 verbatim, RUNTIME segLen) -------
// grid (N/256, kseg, B), block 256 = 4 independent waves, 64 queries each.
// segLen/kseg MUST stay runtime args: a compile-time trip count fully
// unrolls the K-loop, hoists 64 short8 loads, blows VGPR past the 256
// cliff and halves occupancy (R6/R9 = +27 us regression).
__global__ __launch_bounds__(256) void attn_kernel(
    const short* __restrict__ q_t, const short* __restrict__ k_t,
    const short* __restrict__ v_b, short* __restrict__ opart,
    float* __restrict__ lpart, int segLen, int kseg) {
  int b = blockIdx.z, s = blockIdx.y;
  int l = threadIdx.x & 63;
  int q0 = blockIdx.x * 256 + (threadIdx.x >> 6) * 64;
  int lo5 = l & 31;
  int hi = l >> 5;
  const short* qp = q_t + (size_t)b * N * C;
  const short* kp = k_t + (size_t)b * N * C;
  const short* vp = v_b + (size_t)b * C * N;
  short8 qf[2][4];
#pragma unroll
  for (int qt = 0; qt < 2; ++qt)
#pragma unroll
    for (int t = 0; t < 4; ++t)
      qf[qt][t] = *(const short8*)&qp[(size_t)(q0 + qt * 32 + lo5) * C + t * 16 + hi * 8];
  f32x16 oacc00, oacc01, oacc10, oacc11;
#pragma unroll
  for (int i = 0; i < 16; ++i) { oacc00[i] = 0.f; oacc01[i] = 0.f; oacc10[i] = 0.f; oacc11[i] = 0.f; }
  float lsum[2] = {0.f, 0.f};
  int kbase = s * segLen;
  for (int kc = 0; kc < segLen; kc += 32) {
    int k0 = kbase + kc;
    short8 kf[4];
#pragma unroll
    for (int t = 0; t < 4; ++t)
      kf[t] = *(const short8*)&kp[(size_t)(k0 + lo5) * C + t * 16 + hi * 8];
    short8 vf[4];
    vf[0] = *(const short8*)&vp[(size_t)(lo5) * N + k0 + hi * 8];
    vf[1] = *(const short8*)&vp[(size_t)(32 + lo5) * N + k0 + hi * 8];
    vf[2] = *(const short8*)&vp[(size_t)(lo5) * N + k0 + 16 + hi * 8];
    vf[3] = *(const short8*)&vp[(size_t)(32 + lo5) * N + k0 + 16 + hi * 8];
    f32x16 sacc[2];
#pragma unroll
    for (int i = 0; i < 16; ++i) { sacc[0][i] = 0.f; sacc[1][i] = 0.f; }
#pragma unroll
    for (int t = 0; t < 4; ++t) {
      sacc[0] = __builtin_amdgcn_mfma_f32_32x32x16_bf16(kf[t], qf[0][t], sacc[0], 0, 0, 0);
      sacc[1] = __builtin_amdgcn_mfma_f32_32x32x16_bf16(kf[t], qf[1][t], sacc[1], 0, 0, 0);
    }
    short8 pf00, pf01, pf10, pf11;
    softpack(sacc[0], hi, lsum[0], pf00, pf01);
    softpack(sacc[1], hi, lsum[1], pf10, pf11);
    oacc00 = __builtin_amdgcn_mfma_f32_32x32x16_bf16(vf[0], pf00, oacc00, 0, 0, 0);
    oacc01 = __builtin_amdgcn_mfma_f32_32x32x16_bf16(vf[1], pf00, oacc01, 0, 0, 0);
    oacc10 = __builtin_amdgcn_mfma_f32_32x32x16_bf16(vf[0], pf10, oacc10, 0, 0, 0);
    oacc11 = __builtin_amdgcn_mfma_f32_32x32x16_bf16(vf[1], pf10, oacc11, 0, 0, 0);
    oacc00 = __builtin_amdgcn_mfma_f32_32x32x16_bf16(vf[2], pf01, oacc00, 0, 0, 0);
    oacc01 = __builtin_amdgcn_mfma_f32_32x32x16_bf16(vf[3], pf01, oacc01, 0, 0, 0);
    oacc10 = __builtin_amdgcn_mfma_f32_32x32x16_bf16(vf[2], pf11, oacc10, 0, 0, 0);
    oacc11 = __builtin_amdgcn_mfma_f32_32x32x16_bf16(vf[3], pf11, oacc11, 0, 0, 0);
  }
#pragma unroll
  for (int qt = 0; qt < 2; ++qt) {
    lsum[qt] += __shfl_xor(lsum[qt], 32);
    int qq = q0 + qt * 32 + lo5;
    short* op = opart + (size_t)(b * kseg + s) * C * N;
#pragma unroll
    for (int r = 0; r < 16; ++r) {
      int c = (r & 3) + 8 * (r >> 2) + 4 * hi;
      float v0 = (qt == 0) ? oacc00[r] : oacc10[r];
      float v1 = (qt == 0) ? oacc01[r] : oacc11[r];
      op[(size_t)c * N + qq] = f2bf(v0);
      op[(size_t)(c + 32) * N + qq] = f2bf(v1);
    }
    if (hi == 0) lpart[(size_t)(b * kseg + s) * N + qq] = lsum[qt];
  }
}

// ---------------- fused merge + proj conv + residual (R6/R9 body) ----------
// grid (N/64, 2, B), block 256 = 64 pos x 4 waves; each wave owns 8 outputs
// (wave-uniform o-range -> proj weights stay scalar-loaded).
__global__ __launch_bounds__(256) void mergeproj_kernel(
    const short* __restrict__ opart, const float* __restrict__ lpart,
    const float* __restrict__ pw, const float* __restrict__ pb,
    const float* __restrict__ x, float* __restrict__ out, int kseg) {
  int b = blockIdx.z;
  int pos = blockIdx.x * 64 + (threadIdx.x & 63);
  int o0 = blockIdx.y * 32 + (threadIdx.x >> 6) * 8;

  // total attention weight for this query position
  float L = 0.f;
  for (int s = 0; s < kseg; ++s) L += lpart[(size_t)(b * kseg + s) * N + pos];
  float invL = 1.f / L;

  float acc[8];
#pragma unroll
  for (int j = 0; j < 8; ++j) acc[j] = 0.f;

  const short* opb = opart + (size_t)b * kseg * C * N + pos;
#pragma unroll
  for (int c = 0; c < C; ++c) {
    float a = 0.f;
    for (int s = 0; s < kseg; ++s)
      a += bf2f(opb[((size_t)s * C + c) * N]);
    a *= invL;
#pragma unroll
    for (int j = 0; j < 8; ++j)
      acc[j] = fmaf(pw[(o0 + j) * C + c], a, acc[j]);
  }
#pragma unroll
  for (int j = 0; j < 8; ++j) {
    size_t oi = (size_t)(b * C + o0 + j) * N + pos;
    out[oi] = x[oi] + acc[j] + pb[o0 + j];
  }
}

extern "C" void kernel_launch(void* const* d_in, const int* in_sizes, int n_in,
                              void* d_out, int out_size, void* d_ws, size_t ws_size,
                              hipStream_t stream) {
  const float* x      = (const float*)d_in[0];
  const float* norm_w = (const float*)d_in[1];
  const float* norm_b = (const float*)d_in[2];
  const float* q_w    = (const float*)d_in[3];
  const float* q_b    = (const float*)d_in[4];
  const float* k_w    = (const float*)d_in[5];
  const float* k_b    = (const float*)d_in[6];
  const float* v_w    = (const float*)d_in[7];
  const float* v_b    = (const float*)d_in[8];
  const float* proj_w = (const float*)d_in[9];
  const float* proj_b = (const float*)d_in[10];
  float* out = (float*)d_out;

  const size_t BCN = (size_t)B * C * N;   // 524288

  // runtime kseg (R4 pattern — keeps segLen a runtime value for attn)
  int kseg = KSEG;
  auto need = [&](int s) -> size_t {
    return BCN * 2 * 3 + 1024 * 8 + (size_t)s * B * N * 4 + (size_t)s * BCN * 2;
  };
  while (kseg > 1 && need(kseg) > ws_size) kseg >>= 1;
  int segLen = N / kseg;

  short* q_t   = (short*)d_ws;
  short* k_t   = q_t + BCN;
  short* vbuf  = k_t + BCN;
  float2* part = (float2*)(vbuf + BCN);           // 512 float2
  float* lpart = (float*)(part + 512);            // kseg*B*N floats
  short* opart = (short*)(lpart + (size_t)kseg * B * N);

  gn_part_kernel<<<512, 256, 0, stream>>>(x, part);

  qkvf_kernel<<<dim3(N / 256, C / 8, B), 256, 0, stream>>>(
      x, part, norm_w, norm_b, q_w, q_b, k_w, k_b, v_w, v_b, q_t, k_t, vbuf);

  attn_kernel<<<dim3(N / 256, kseg, B), 256, 0, stream>>>(
      q_t, k_t, vbuf, opart, lpart, segLen, kseg);

  mergeproj_kernel<<<dim3(N / 64, 2, B), 256, 0, stream>>>(
      opart, lpart, proj_w, proj_b, x, out, kseg);
}

// Round 11
// 94.198 us; speedup vs baseline: 3.4877x; 3.4877x over previous
//
#include <hip/hip_runtime.h>
#include <hip/hip_bf16.h>

#define B 2
#define C 64
#define N 4096          // 16*16*16
#define EPS 1e-5f
#define KSEG 16
// 0.125 * log2(e): fold softmax scale AND exp->exp2 conversion into q
#define QSCALE_LOG2E 0.18033688f

using short8 = __attribute__((ext_vector_type(8))) short;
using f32x16 = __attribute__((ext_vector_type(16))) float;

__device__ inline short f2bf(float f) {
  __hip_bfloat16 h = __float2bfloat16(f);
  union { __hip_bfloat16 h; short s; } u; u.h = h; return u.s;
}
__device__ inline float bf2f(short s) {
  union { unsigned u; float f; } u;
  u.u = ((unsigned)(unsigned short)s) << 16;
  return u.f;
}
__device__ inline int packbf(float a, float b) {
  return (int)((unsigned short)f2bf(a) | ((unsigned)(unsigned short)f2bf(b) << 16));
}

// softmax (exp2 domain, no max) + pack P into two PV B-fragments (R4 verbatim)
__device__ inline void softpack(f32x16& s, int hi, float& lsum,
                                short8& p0, short8& p1) {
  float ps = 0.f;
#pragma unroll
  for (int i = 0; i < 16; ++i) { s[i] = exp2f(s[i]); ps += s[i]; }
  lsum += ps;   // cross-pair shfl deferred to epilogue (linear)
  union U { int i[4]; short8 v; } f0, f1;
  {
    int x0 = packbf(s[0], s[1]), z0 = packbf(s[2], s[3]);
    int y0 = packbf(s[4], s[5]), w0 = packbf(s[6], s[7]);
    int xs = __shfl_xor(x0, 32), zs = __shfl_xor(z0, 32);
    int ys = __shfl_xor(y0, 32), ws2 = __shfl_xor(w0, 32);
    f0.i[0] = hi ? ys : x0; f0.i[1] = hi ? ws2 : z0;
    f0.i[2] = hi ? y0 : xs; f0.i[3] = hi ? w0 : zs;
  }
  {
    int x0 = packbf(s[8], s[9]), z0 = packbf(s[10], s[11]);
    int y0 = packbf(s[12], s[13]), w0 = packbf(s[14], s[15]);
    int xs = __shfl_xor(x0, 32), zs = __shfl_xor(z0, 32);
    int ys = __shfl_xor(y0, 32), ws2 = __shfl_xor(w0, 32);
    f1.i[0] = hi ? ys : x0; f1.i[1] = hi ? ws2 : z0;
    f1.i[2] = hi ? y0 : xs; f1.i[3] = hi ? w0 : zs;
  }
  p0 = f0.v; p1 = f1.v;
}

// ---------------- GroupNorm partial sums (R4 verbatim) ----------------
__global__ __launch_bounds__(256) void gn_part_kernel(
    const float* __restrict__ x, float2* __restrict__ part) {
  int blk = blockIdx.x;
  int bg = blk >> 4, sl = blk & 15;
  const float4* xv = (const float4*)(x + (size_t)bg * 4 * N) + sl * 256;
  int tid = threadIdx.x;
  float4 v = xv[tid];
  float s = v.x + v.y + v.z + v.w;
  float s2 = v.x * v.x + v.y * v.y + v.z * v.z + v.w * v.w;
  __shared__ float ss[256], ss2[256];
  ss[tid] = s; ss2[tid] = s2;
  __syncthreads();
  for (int st = 128; st > 0; st >>= 1) {
    if (tid < st) { ss[tid] += ss[tid + st]; ss2[tid] += ss2[tid + st]; }
    __syncthreads();
  }
  if (tid == 0) part[blk] = make_float2(ss[0], ss2[0]);
}

// ------------- fused gn-finalize + norm + q/k/v conv (R6-proven fold) -------
__global__ __launch_bounds__(256) void qkvf_kernel(
    const float* __restrict__ x, const float2* __restrict__ part,
    const float* __restrict__ gw, const float* __restrict__ gb,
    const float* __restrict__ qw, const float* __restrict__ qb,
    const float* __restrict__ kw, const float* __restrict__ kb,
    const float* __restrict__ vw, const float* __restrict__ vb,
    short* __restrict__ q_t, short* __restrict__ k_t, short* __restrict__ v_b) {
  int o0 = blockIdx.y * 8, b = blockIdx.z;
  int tid = threadIdx.x;
  __shared__ float asl[C], bsl[C];
  if (tid < C) {
    int c = tid, g = c >> 2;
    int bg = b * 16 + g;
    float s = 0.f, s2 = 0.f;
#pragma unroll
    for (int sl = 0; sl < 16; ++sl) {
      float2 p = part[bg * 16 + sl];
      s += p.x; s2 += p.y;
    }
    float mean = s * (1.f / 16384.f);
    float var = s2 * (1.f / 16384.f) - mean * mean;
    float inv = rsqrtf(var + EPS);
    float a = inv * gw[c];
    asl[c] = a;
    bsl[c] = gb[c] - mean * a;
  }
  __syncthreads();
  int pos = blockIdx.x * 256 + tid;
  const float* xp = x + (size_t)b * C * N + pos;
  float sq[8], sk[8], sv[8];
#pragma unroll
  for (int j = 0; j < 8; ++j) { sq[j] = 0.f; sk[j] = 0.f; sv[j] = 0.f; }
#pragma unroll
  for (int c = 0; c < C; ++c) {
    float hv = fmaf(xp[(size_t)c * N], asl[c], bsl[c]);
#pragma unroll
    for (int j = 0; j < 8; ++j) {
      sq[j] = fmaf(qw[(o0 + j) * C + c], hv, sq[j]);
      sk[j] = fmaf(kw[(o0 + j) * C + c], hv, sk[j]);
      sv[j] = fmaf(vw[(o0 + j) * C + c], hv, sv[j]);
    }
  }
  size_t ti = ((size_t)b * N + pos) * C;
  short8 qv, kv;
#pragma unroll
  for (int j = 0; j < 8; ++j) {
    qv[j] = f2bf((sq[j] + qb[o0 + j]) * QSCALE_LOG2E);
    kv[j] = f2bf(sk[j] + kb[o0 + j]);
  }
  *(short8*)&q_t[ti + o0] = qv;
  *(short8*)&k_t[ti + o0] = kv;
#pragma unroll
  for (int j = 0; j < 8; ++j)
    v_b[((size_t)b * C + o0 + j) * N + pos] = f2bf(sv[j] + vb[o0 + j]);
}

// ---------------- MFMA flash attention (R4 verbatim, RUNTIME segLen) -------
// grid (N/256, kseg, B), block 256 = 4 independent waves, 64 queries each.
// segLen/kseg MUST stay runtime args here: a compile-time trip count fully
// unrolls the K-loop, hoists 64 short8 loads, blows VGPR past the 256
// cliff and halves occupancy (R6/R9 = +27 us regression on this kernel).
__global__ __launch_bounds__(256) void attn_kernel(
    const short* __restrict__ q_t, const short* __restrict__ k_t,
    const short* __restrict__ v_b, short* __restrict__ opart,
    float* __restrict__ lpart, int segLen, int kseg) {
  int b = blockIdx.z, s = blockIdx.y;
  int l = threadIdx.x & 63;
  int q0 = blockIdx.x * 256 + (threadIdx.x >> 6) * 64;
  int lo5 = l & 31;
  int hi = l >> 5;
  const short* qp = q_t + (size_t)b * N * C;
  const short* kp = k_t + (size_t)b * N * C;
  const short* vp = v_b + (size_t)b * C * N;
  short8 qf[2][4];
#pragma unroll
  for (int qt = 0; qt < 2; ++qt)
#pragma unroll
    for (int t = 0; t < 4; ++t)
      qf[qt][t] = *(const short8*)&qp[(size_t)(q0 + qt * 32 + lo5) * C + t * 16 + hi * 8];
  f32x16 oacc00, oacc01, oacc10, oacc11;
#pragma unroll
  for (int i = 0; i < 16; ++i) { oacc00[i] = 0.f; oacc01[i] = 0.f; oacc10[i] = 0.f; oacc11[i] = 0.f; }
  float lsum[2] = {0.f, 0.f};
  int kbase = s * segLen;
  for (int kc = 0; kc < segLen; kc += 32) {
    int k0 = kbase + kc;
    short8 kf[4];
#pragma unroll
    for (int t = 0; t < 4; ++t)
      kf[t] = *(const short8*)&kp[(size_t)(k0 + lo5) * C + t * 16 + hi * 8];
    short8 vf[4];
    vf[0] = *(const short8*)&vp[(size_t)(lo5) * N + k0 + hi * 8];
    vf[1] = *(const short8*)&vp[(size_t)(32 + lo5) * N + k0 + hi * 8];
    vf[2] = *(const short8*)&vp[(size_t)(lo5) * N + k0 + 16 + hi * 8];
    vf[3] = *(const short8*)&vp[(size_t)(32 + lo5) * N + k0 + 16 + hi * 8];
    f32x16 sacc[2];
#pragma unroll
    for (int i = 0; i < 16; ++i) { sacc[0][i] = 0.f; sacc[1][i] = 0.f; }
#pragma unroll
    for (int t = 0; t < 4; ++t) {
      sacc[0] = __builtin_amdgcn_mfma_f32_32x32x16_bf16(kf[t], qf[0][t], sacc[0], 0, 0, 0);
      sacc[1] = __builtin_amdgcn_mfma_f32_32x32x16_bf16(kf[t], qf[1][t], sacc[1], 0, 0, 0);
    }
    short8 pf00, pf01, pf10, pf11;
    softpack(sacc[0], hi, lsum[0], pf00, pf01);
    softpack(sacc[1], hi, lsum[1], pf10, pf11);
    oacc00 = __builtin_amdgcn_mfma_f32_32x32x16_bf16(vf[0], pf00, oacc00, 0, 0, 0);
    oacc01 = __builtin_amdgcn_mfma_f32_32x32x16_bf16(vf[1], pf00, oacc01, 0, 0, 0);
    oacc10 = __builtin_amdgcn_mfma_f32_32x32x16_bf16(vf[0], pf10, oacc10, 0, 0, 0);
    oacc11 = __builtin_amdgcn_mfma_f32_32x32x16_bf16(vf[1], pf10, oacc11, 0, 0, 0);
    oacc00 = __builtin_amdgcn_mfma_f32_32x32x16_bf16(vf[2], pf01, oacc00, 0, 0, 0);
    oacc01 = __builtin_amdgcn_mfma_f32_32x32x16_bf16(vf[3], pf01, oacc01, 0, 0, 0);
    oacc10 = __builtin_amdgcn_mfma_f32_32x32x16_bf16(vf[2], pf11, oacc10, 0, 0, 0);
    oacc11 = __builtin_amdgcn_mfma_f32_32x32x16_bf16(vf[3], pf11, oacc11, 0, 0, 0);
  }
#pragma unroll
  for (int qt = 0; qt < 2; ++qt) {
    lsum[qt] += __shfl_xor(lsum[qt], 32);
    int qq = q0 + qt * 32 + lo5;
    short* op = opart + (size_t)(b * kseg + s) * C * N;
#pragma unroll
    for (int r = 0; r < 16; ++r) {
      int c = (r & 3) + 8 * (r >> 2) + 4 * hi;
      float v0 = (qt == 0) ? oacc00[r] : oacc10[r];
      float v1 = (qt == 0) ? oacc01[r] : oacc11[r];
      op[(size_t)c * N + qq] = f2bf(v0);
      op[(size_t)(c + 32) * N + qq] = f2bf(v1);
    }
    if (hi == 0) lpart[(size_t)(b * kseg + s) * N + qq] = lsum[qt];
  }
}

// ---------------- fused merge + proj conv + residual ----------------
// COMPILE-TIME KSEG here (opposite of attn!): the unrolled s-loop lets the
// compiler batch the 16 independent opart loads per c; runtime kseg (R10)
// serialized them -> 270 us, VGPR 256. grid (N/64, 2, B), block 256.
__global__ __launch_bounds__(256) void mergeproj_kernel(
    const short* __restrict__ opart, const float* __restrict__ lpart,
    const float* __restrict__ pw, const float* __restrict__ pb,
    const float* __restrict__ x, float* __restrict__ out) {
  int b = blockIdx.z;
  int pos = blockIdx.x * 64 + (threadIdx.x & 63);
  int o0 = blockIdx.y * 32 + (threadIdx.x >> 6) * 8;

  // total attention weight for this query position
  float L = 0.f;
#pragma unroll
  for (int s = 0; s < KSEG; ++s) L += lpart[(size_t)(b * KSEG + s) * N + pos];
  float invL = 1.f / L;

  float acc[8];
#pragma unroll
  for (int j = 0; j < 8; ++j) acc[j] = 0.f;

  const short* opb = opart + (size_t)b * KSEG * C * N + pos;
#pragma unroll
  for (int c = 0; c < C; ++c) {
    float a = 0.f;
#pragma unroll
    for (int s = 0; s < KSEG; ++s)
      a += bf2f(opb[((size_t)s * C + c) * N]);
    a *= invL;
#pragma unroll
    for (int j = 0; j < 8; ++j)
      acc[j] = fmaf(pw[(o0 + j) * C + c], a, acc[j]);
  }
#pragma unroll
  for (int j = 0; j < 8; ++j) {
    size_t oi = (size_t)(b * C + o0 + j) * N + pos;
    out[oi] = x[oi] + acc[j] + pb[o0 + j];
  }
}

extern "C" void kernel_launch(void* const* d_in, const int* in_sizes, int n_in,
                              void* d_out, int out_size, void* d_ws, size_t ws_size,
                              hipStream_t stream) {
  const float* x      = (const float*)d_in[0];
  const float* norm_w = (const float*)d_in[1];
  const float* norm_b = (const float*)d_in[2];
  const float* q_w    = (const float*)d_in[3];
  const float* q_b    = (const float*)d_in[4];
  const float* k_w    = (const float*)d_in[5];
  const float* k_b    = (const float*)d_in[6];
  const float* v_w    = (const float*)d_in[7];
  const float* v_b    = (const float*)d_in[8];
  const float* proj_w = (const float*)d_in[9];
  const float* proj_b = (const float*)d_in[10];
  float* out = (float*)d_out;

  const size_t BCN = (size_t)B * C * N;   // 524288

  // kseg fixed at 16 (~30 MB of ws; ws is ~268 MB). attn still receives it
  // as a runtime value to keep its K-loop un-unrolled.
  int kseg = KSEG;
  int segLen = N / kseg;

  short* q_t   = (short*)d_ws;
  short* k_t   = q_t + BCN;
  short* vbuf  = k_t + BCN;
  float2* part = (float2*)(vbuf + BCN);           // 512 float2
  float* lpart = (float*)(part + 512);            // kseg*B*N floats
  short* opart = (short*)(lpart + (size_t)KSEG * B * N);

  gn_part_kernel<<<512, 256, 0, stream>>>(x, part);

  qkvf_kernel<<<dim3(N / 256, C / 8, B), 256, 0, stream>>>(
      x, part, norm_w, norm_b, q_w, q_b, k_w, k_b, v_w, v_b, q_t, k_t, vbuf);

  attn_kernel<<<dim3(N / 256, kseg, B), 256, 0, stream>>>(
      q_t, k_t, vbuf, opart, lpart, segLen, kseg);

  mergeproj_kernel<<<dim3(N / 64, 2, B), 256, 0, stream>>>(
      opart, lpart, proj_w, proj_b, x, out);
}

// Round 12
// 67.805 us; speedup vs baseline: 4.8453x; 1.3892x over previous
//
#include <hip/hip_runtime.h>
#include <hip/hip_bf16.h>

#define B 2
#define C 64
#define N 4096          // 16*16*16
#define EPS 1e-5f
#define KSEG 16
#define POSB 32         // pos per mergeproj block
// 0.125 * log2(e): fold softmax scale AND exp->exp2 conversion into q
#define QSCALE_LOG2E 0.18033688f

using short8 = __attribute__((ext_vector_type(8))) short;
using f32x16 = __attribute__((ext_vector_type(16))) float;

__device__ inline short f2bf(float f) {
  __hip_bfloat16 h = __float2bfloat16(f);
  union { __hip_bfloat16 h; short s; } u; u.h = h; return u.s;
}
__device__ inline float bf2f(short s) {
  union { unsigned u; float f; } u;
  u.u = ((unsigned)(unsigned short)s) << 16;
  return u.f;
}
__device__ inline int packbf(float a, float b) {
  return (int)((unsigned short)f2bf(a) | ((unsigned)(unsigned short)f2bf(b) << 16));
}

// softmax (exp2 domain, no max) + pack P into two PV B-fragments (R4 verbatim)
__device__ inline void softpack(f32x16& s, int hi, float& lsum,
                                short8& p0, short8& p1) {
  float ps = 0.f;
#pragma unroll
  for (int i = 0; i < 16; ++i) { s[i] = exp2f(s[i]); ps += s[i]; }
  lsum += ps;   // cross-pair shfl deferred to epilogue (linear)
  union U { int i[4]; short8 v; } f0, f1;
  {
    int x0 = packbf(s[0], s[1]), z0 = packbf(s[2], s[3]);
    int y0 = packbf(s[4], s[5]), w0 = packbf(s[6], s[7]);
    int xs = __shfl_xor(x0, 32), zs = __shfl_xor(z0, 32);
    int ys = __shfl_xor(y0, 32), ws2 = __shfl_xor(w0, 32);
    f0.i[0] = hi ? ys : x0; f0.i[1] = hi ? ws2 : z0;
    f0.i[2] = hi ? y0 : xs; f0.i[3] = hi ? w0 : zs;
  }
  {
    int x0 = packbf(s[8], s[9]), z0 = packbf(s[10], s[11]);
    int y0 = packbf(s[12], s[13]), w0 = packbf(s[14], s[15]);
    int xs = __shfl_xor(x0, 32), zs = __shfl_xor(z0, 32);
    int ys = __shfl_xor(y0, 32), ws2 = __shfl_xor(w0, 32);
    f1.i[0] = hi ? ys : x0; f1.i[1] = hi ? ws2 : z0;
    f1.i[2] = hi ? y0 : xs; f1.i[3] = hi ? w0 : zs;
  }
  p0 = f0.v; p1 = f1.v;
}

// ---------------- GroupNorm partial sums (R4 verbatim) ----------------
__global__ __launch_bounds__(256) void gn_part_kernel(
    const float* __restrict__ x, float2* __restrict__ part) {
  int blk = blockIdx.x;
  int bg = blk >> 4, sl = blk & 15;
  const float4* xv = (const float4*)(x + (size_t)bg * 4 * N) + sl * 256;
  int tid = threadIdx.x;
  float4 v = xv[tid];
  float s = v.x + v.y + v.z + v.w;
  float s2 = v.x * v.x + v.y * v.y + v.z * v.z + v.w * v.w;
  __shared__ float ss[256], ss2[256];
  ss[tid] = s; ss2[tid] = s2;
  __syncthreads();
  for (int st = 128; st > 0; st >>= 1) {
    if (tid < st) { ss[tid] += ss[tid + st]; ss2[tid] += ss2[tid + st]; }
    __syncthreads();
  }
  if (tid == 0) part[blk] = make_float2(ss[0], ss2[0]);
}

// ------------- fused gn-finalize + norm + q/k/v conv (R6-proven fold) -------
__global__ __launch_bounds__(256) void qkvf_kernel(
    const float* __restrict__ x, const float2* __restrict__ part,
    const float* __restrict__ gw, const float* __restrict__ gb,
    const float* __restrict__ qw, const float* __restrict__ qb,
    const float* __restrict__ kw, const float* __restrict__ kb,
    const float* __restrict__ vw, const float* __restrict__ vb,
    short* __restrict__ q_t, short* __restrict__ k_t, short* __restrict__ v_b) {
  int o0 = blockIdx.y * 8, b = blockIdx.z;
  int tid = threadIdx.x;
  __shared__ float asl[C], bsl[C];
  if (tid < C) {
    int c = tid, g = c >> 2;
    int bg = b * 16 + g;
    float s = 0.f, s2 = 0.f;
#pragma unroll
    for (int sl = 0; sl < 16; ++sl) {
      float2 p = part[bg * 16 + sl];
      s += p.x; s2 += p.y;
    }
    float mean = s * (1.f / 16384.f);
    float var = s2 * (1.f / 16384.f) - mean * mean;
    float inv = rsqrtf(var + EPS);
    float a = inv * gw[c];
    asl[c] = a;
    bsl[c] = gb[c] - mean * a;
  }
  __syncthreads();
  int pos = blockIdx.x * 256 + tid;
  const float* xp = x + (size_t)b * C * N + pos;
  float sq[8], sk[8], sv[8];
#pragma unroll
  for (int j = 0; j < 8; ++j) { sq[j] = 0.f; sk[j] = 0.f; sv[j] = 0.f; }
#pragma unroll
  for (int c = 0; c < C; ++c) {
    float hv = fmaf(xp[(size_t)c * N], asl[c], bsl[c]);
#pragma unroll
    for (int j = 0; j < 8; ++j) {
      sq[j] = fmaf(qw[(o0 + j) * C + c], hv, sq[j]);
      sk[j] = fmaf(kw[(o0 + j) * C + c], hv, sk[j]);
      sv[j] = fmaf(vw[(o0 + j) * C + c], hv, sv[j]);
    }
  }
  size_t ti = ((size_t)b * N + pos) * C;
  short8 qv, kv;
#pragma unroll
  for (int j = 0; j < 8; ++j) {
    qv[j] = f2bf((sq[j] + qb[o0 + j]) * QSCALE_LOG2E);
    kv[j] = f2bf(sk[j] + kb[o0 + j]);
  }
  *(short8*)&q_t[ti + o0] = qv;
  *(short8*)&k_t[ti + o0] = kv;
#pragma unroll
  for (int j = 0; j < 8; ++j)
    v_b[((size_t)b * C + o0 + j) * N + pos] = f2bf(sv[j] + vb[o0 + j]);
}

// ---------------- MFMA flash attention (R4 verbatim, RUNTIME segLen) -------
// grid (N/256, kseg, B), block 256 = 4 independent waves, 64 queries each.
__global__ __launch_bounds__(256) void attn_kernel(
    const short* __restrict__ q_t, const short* __restrict__ k_t,
    const short* __restrict__ v_b, short* __restrict__ opart,
    float* __restrict__ lpart, int segLen, int kseg) {
  int b = blockIdx.z, s = blockIdx.y;
  int l = threadIdx.x & 63;
  int q0 = blockIdx.x * 256 + (threadIdx.x >> 6) * 64;
  int lo5 = l & 31;
  int hi = l >> 5;
  const short* qp = q_t + (size_t)b * N * C;
  const short* kp = k_t + (size_t)b * N * C;
  const short* vp = v_b + (size_t)b * C * N;
  short8 qf[2][4];
#pragma unroll
  for (int qt = 0; qt < 2; ++qt)
#pragma unroll
    for (int t = 0; t < 4; ++t)
      qf[qt][t] = *(const short8*)&qp[(size_t)(q0 + qt * 32 + lo5) * C + t * 16 + hi * 8];
  f32x16 oacc00, oacc01, oacc10, oacc11;
#pragma unroll
  for (int i = 0; i < 16; ++i) { oacc00[i] = 0.f; oacc01[i] = 0.f; oacc10[i] = 0.f; oacc11[i] = 0.f; }
  float lsum[2] = {0.f, 0.f};
  int kbase = s * segLen;
  for (int kc = 0; kc < segLen; kc += 32) {
    int k0 = kbase + kc;
    short8 kf[4];
#pragma unroll
    for (int t = 0; t < 4; ++t)
      kf[t] = *(const short8*)&kp[(size_t)(k0 + lo5) * C + t * 16 + hi * 8];
    short8 vf[4];
    vf[0] = *(const short8*)&vp[(size_t)(lo5) * N + k0 + hi * 8];
    vf[1] = *(const short8*)&vp[(size_t)(32 + lo5) * N + k0 + hi * 8];
    vf[2] = *(const short8*)&vp[(size_t)(lo5) * N + k0 + 16 + hi * 8];
    vf[3] = *(const short8*)&vp[(size_t)(32 + lo5) * N + k0 + 16 + hi * 8];
    f32x16 sacc[2];
#pragma unroll
    for (int i = 0; i < 16; ++i) { sacc[0][i] = 0.f; sacc[1][i] = 0.f; }
#pragma unroll
    for (int t = 0; t < 4; ++t) {
      sacc[0] = __builtin_amdgcn_mfma_f32_32x32x16_bf16(kf[t], qf[0][t], sacc[0], 0, 0, 0);
      sacc[1] = __builtin_amdgcn_mfma_f32_32x32x16_bf16(kf[t], qf[1][t], sacc[1], 0, 0, 0);
    }
    short8 pf00, pf01, pf10, pf11;
    softpack(sacc[0], hi, lsum[0], pf00, pf01);
    softpack(sacc[1], hi, lsum[1], pf10, pf11);
    oacc00 = __builtin_amdgcn_mfma_f32_32x32x16_bf16(vf[0], pf00, oacc00, 0, 0, 0);
    oacc01 = __builtin_amdgcn_mfma_f32_32x32x16_bf16(vf[1], pf00, oacc01, 0, 0, 0);
    oacc10 = __builtin_amdgcn_mfma_f32_32x32x16_bf16(vf[0], pf10, oacc10, 0, 0, 0);
    oacc11 = __builtin_amdgcn_mfma_f32_32x32x16_bf16(vf[1], pf10, oacc11, 0, 0, 0);
    oacc00 = __builtin_amdgcn_mfma_f32_32x32x16_bf16(vf[2], pf01, oacc00, 0, 0, 0);
    oacc01 = __builtin_amdgcn_mfma_f32_32x32x16_bf16(vf[3], pf01, oacc01, 0, 0, 0);
    oacc10 = __builtin_amdgcn_mfma_f32_32x32x16_bf16(vf[2], pf11, oacc10, 0, 0, 0);
    oacc11 = __builtin_amdgcn_mfma_f32_32x32x16_bf16(vf[3], pf11, oacc11, 0, 0, 0);
  }
#pragma unroll
  for (int qt = 0; qt < 2; ++qt) {
    lsum[qt] += __shfl_xor(lsum[qt], 32);
    int qq = q0 + qt * 32 + lo5;
    short* op = opart + (size_t)(b * kseg + s) * C * N;
#pragma unroll
    for (int r = 0; r < 16; ++r) {
      int c = (r & 3) + 8 * (r >> 2) + 4 * hi;
      float v0 = (qt == 0) ? oacc00[r] : oacc10[r];
      float v1 = (qt == 0) ? oacc01[r] : oacc11[r];
      op[(size_t)c * N + qq] = f2bf(v0);
      op[(size_t)(c + 32) * N + qq] = f2bf(v1);
    }
    if (hi == 0) lpart[(size_t)(b * kseg + s) * N + qq] = lsum[qt];
  }
}

// ---------------- fused merge + proj via LDS handoff ----------------
// grid (N/POSB, B), block 256. R11's version issued 1024 scalar strided
// loads/thread (VMEM-issue-bound, ~35us). Here: phase A merges with 16
// vectorized short8 loads/thread into LDS; phase B projs from LDS.
// invL factored out of the linear proj -> applied once in the epilogue.
__global__ __launch_bounds__(256) void mergeproj_kernel(
    const short* __restrict__ opart, const float* __restrict__ lpart,
    const float* __restrict__ pw, const float* __restrict__ pb,
    const float* __restrict__ x, float* __restrict__ out) {
  int b = blockIdx.y;
  int pos0 = blockIdx.x * POSB;
  int tid = threadIdx.x;

  __shared__ float ldsA[C][POSB];    // merged (unnormalized) [c][pos]
  __shared__ float ldsW[C][C + 1];   // proj weights, padded row (+1) vs banks
  __shared__ float ldsL[POSB];       // 1/L per pos

  // stage proj weights (4 KB, coalesced float4 global reads)
#pragma unroll
  for (int i = 0; i < 4; ++i) {
    int idx = i * 1024 + tid * 4;
    float4 w4 = *(const float4*)&pw[idx];
    int o = idx >> 6, c = idx & 63;
    ldsW[o][c] = w4.x; ldsW[o][c + 1] = w4.y;
    ldsW[o][c + 2] = w4.z; ldsW[o][c + 3] = w4.w;
  }
  // per-pos total attention weight
  if (tid < POSB) {
    float L = 0.f;
#pragma unroll
    for (int s = 0; s < KSEG; ++s)
      L += lpart[(size_t)(b * KSEG + s) * N + pos0 + tid];
    ldsL[tid] = 1.f / L;
  }

  // phase A: merge KSEG partials, thread = (c, 8 pos)
  int c = tid >> 2, pg = tid & 3;
  {
    float o8[8];
#pragma unroll
    for (int j = 0; j < 8; ++j) o8[j] = 0.f;
    const short* opb = opart + ((size_t)b * KSEG * C + c) * N + pos0 + pg * 8;
#pragma unroll
    for (int s = 0; s < KSEG; ++s) {
      short8 v = *(const short8*)&opb[(size_t)s * C * N];
#pragma unroll
      for (int j = 0; j < 8; ++j) o8[j] += bf2f(v[j]);
    }
    *(float4*)&ldsA[c][pg * 8] = make_float4(o8[0], o8[1], o8[2], o8[3]);
    *(float4*)&ldsA[c][pg * 8 + 4] = make_float4(o8[4], o8[5], o8[6], o8[7]);
  }
  __syncthreads();

  // phase B: proj, thread = (o, 8 pos). ldsA row reads are wave-uniform
  // (broadcast); ldsW pad makes the 16 o-addresses hit 16 distinct banks.
  int o = tid >> 2;
  float4 acc0 = make_float4(0.f, 0.f, 0.f, 0.f);
  float4 acc1 = make_float4(0.f, 0.f, 0.f, 0.f);
#pragma unroll
  for (int cc = 0; cc < C; ++cc) {
    float w = ldsW[o][cc];
    float4 a0 = *(const float4*)&ldsA[cc][pg * 8];
    float4 a1 = *(const float4*)&ldsA[cc][pg * 8 + 4];
    acc0.x = fmaf(w, a0.x, acc0.x); acc0.y = fmaf(w, a0.y, acc0.y);
    acc0.z = fmaf(w, a0.z, acc0.z); acc0.w = fmaf(w, a0.w, acc0.w);
    acc1.x = fmaf(w, a1.x, acc1.x); acc1.y = fmaf(w, a1.y, acc1.y);
    acc1.z = fmaf(w, a1.z, acc1.z); acc1.w = fmaf(w, a1.w, acc1.w);
  }
  float pbo = pb[o];
  size_t oi = (size_t)(b * C + o) * N + pos0 + pg * 8;
  float4 xv0 = *(const float4*)&x[oi];
  float4 xv1 = *(const float4*)&x[oi + 4];
  float4 r0, r1;
  r0.x = xv0.x + acc0.x * ldsL[pg * 8 + 0] + pbo;
  r0.y = xv0.y + acc0.y * ldsL[pg * 8 + 1] + pbo;
  r0.z = xv0.z + acc0.z * ldsL[pg * 8 + 2] + pbo;
  r0.w = xv0.w + acc0.w * ldsL[pg * 8 + 3] + pbo;
  r1.x = xv1.x + acc1.x * ldsL[pg * 8 + 4] + pbo;
  r1.y = xv1.y + acc1.y * ldsL[pg * 8 + 5] + pbo;
  r1.z = xv1.z + acc1.z * ldsL[pg * 8 + 6] + pbo;
  r1.w = xv1.w + acc1.w * ldsL[pg * 8 + 7] + pbo;
  *(float4*)&out[oi] = r0;
  *(float4*)&out[oi + 4] = r1;
}

extern "C" void kernel_launch(void* const* d_in, const int* in_sizes, int n_in,
                              void* d_out, int out_size, void* d_ws, size_t ws_size,
                              hipStream_t stream) {
  const float* x      = (const float*)d_in[0];
  const float* norm_w = (const float*)d_in[1];
  const float* norm_b = (const float*)d_in[2];
  const float* q_w    = (const float*)d_in[3];
  const float* q_b    = (const float*)d_in[4];
  const float* k_w    = (const float*)d_in[5];
  const float* k_b    = (const float*)d_in[6];
  const float* v_w    = (const float*)d_in[7];
  const float* v_b    = (const float*)d_in[8];
  const float* proj_w = (const float*)d_in[9];
  const float* proj_b = (const float*)d_in[10];
  float* out = (float*)d_out;

  const size_t BCN = (size_t)B * C * N;   // 524288

  int kseg = KSEG;
  int segLen = N / kseg;

  short* q_t   = (short*)d_ws;
  short* k_t   = q_t + BCN;
  short* vbuf  = k_t + BCN;
  float2* part = (float2*)(vbuf + BCN);           // 512 float2
  float* lpart = (float*)(part + 512);            // KSEG*B*N floats
  short* opart = (short*)(lpart + (size_t)KSEG * B * N);

  gn_part_kernel<<<512, 256, 0, stream>>>(x, part);

  qkvf_kernel<<<dim3(N / 256, C / 8, B), 256, 0, stream>>>(
      x, part, norm_w, norm_b, q_w, q_b, k_w, k_b, v_w, v_b, q_t, k_t, vbuf);

  attn_kernel<<<dim3(N / 256, kseg, B), 256, 0, stream>>>(
      q_t, k_t, vbuf, opart, lpart, segLen, kseg);

  mergeproj_kernel<<<dim3(N / POSB, B), 256, 0, stream>>>(
      opart, lpart, proj_w, proj_b, x, out);
}